// Round 13
// baseline (1098.074 us; speedup 1.0000x reference)
//
#include <hip/hip_runtime.h>
#include <hip/hip_bf16.h>

#define BB 512
#define NA 58
#define LAT 64
#define HID 128
#define AF 10
#define NL 2
#define NN (BB*NA)      // 29696
#define NE (NN*16)      // 475136
#define NWT (NE/16)     // 29696 wave-tiles
#define PBLK 768        // persistent blocks (3 per CU)

typedef __attribute__((ext_vector_type(8))) short s8;
typedef __attribute__((ext_vector_type(4))) float f4;

struct CvtDesc {
    const void* src[24];
    float*      dst[24];
    int         len[24];
};

struct PackJobs {
    const float* src[11];
    short*       dst[11];
    int          K[11];
    int          mode[11];   // 0: [K][128] B-frag; 1: edge-w1 concat; 2: [K][64] B-frag
};

__device__ __forceinline__ float siluf(float x) {
    return x * __builtin_amdgcn_rcpf(1.0f + __expf(-x));
}

__device__ __forceinline__ short f2b(float x) {
    __hip_bfloat16 b = __float2bfloat16(x);
    return *(short*)&b;
}

__device__ __forceinline__ float b2f(short s) {
    return __uint_as_float(((unsigned int)(unsigned short)s) << 16);
}

// ---------------------------------------------------------------------------
__global__ void k_detect(const unsigned short* __restrict__ z16,
                         const unsigned int* __restrict__ e32,
                         int* __restrict__ flags) {
    __shared__ int sbf, si64;
    if (threadIdx.x == 0) { sbf = 0; si64 = 0; }
    __syncthreads();
    int c1 = 0, c2 = 0;
    for (int i = threadIdx.x; i < 1024; i += 256) {
        unsigned short v = z16[2*i];
        int e = (v >> 7) & 0xFF;
        if (e >= 100 && e <= 140) c1++;
        if (e32[2*i + 1] == 0u) c2++;
    }
    atomicAdd(&sbf, c1);
    atomicAdd(&si64, c2);
    __syncthreads();
    if (threadIdx.x == 0) {
        flags[0] = (sbf  > 600) ? 1 : 0;
        flags[1] = (si64 > 600) ? 1 : 0;
    }
}

__global__ void k_convert(CvtDesc d, const int* __restrict__ flags) {
    int a = blockIdx.y;
    int i = blockIdx.x * blockDim.x + threadIdx.x;
    int n = d.len[a];
    if (i >= n) return;
    if (flags[0]) {
        d.dst[a][i] = __bfloat162float(((const __hip_bfloat16*)d.src[a])[i]);
    } else {
        d.dst[a][i] = ((const float*)d.src[a])[i];
    }
}

__global__ void k_packall(PackJobs pj) {
    int j = blockIdx.y;
    int idx = blockIdx.x * 256 + threadIdx.x;
    const float* w = pj.src[j];
    short* o = pj.dst[j];
    int mode = pj.mode[j];
    if (mode == 0) {
        int K = pj.K[j];
        if (idx >= 128*K) return;
        int jj = idx & 7;
        int l  = (idx >> 3) & 63;
        int rest = idx >> 9;
        int KC = K >> 5;
        int kc = rest % KC;
        int nt = rest / KC;
        int n = nt*16 + (l & 15);
        int k = kc*32 + (l >> 4)*8 + jj;
        o[idx] = f2b(w[k*128 + n]);
    } else if (mode == 1) {
        if (idx >= 32768) return;
        int jj = idx & 7;
        int l  = (idx >> 3) & 63;
        int rest = idx >> 9;
        int kc = rest & 3;
        int nt = rest >> 2;
        int n = nt*16 + (l & 15);
        int k = kc*32 + (l >> 4)*8 + jj;
        float v = (n < 128) ? w[k*128 + n] : w[(128 + k)*128 + (n - 128)];
        o[idx] = f2b(v);
    } else {
        // head_w1 [128][64] -> N=64 B-frag
        if (idx >= 8192) return;
        int jj = idx & 7;
        int l  = (idx >> 3) & 63;
        int rest = idx >> 9;          // 0..15
        int kc = rest & 3;
        int nt = rest >> 2;           // 0..3
        int n = nt*16 + (l & 15);
        int k = kc*32 + (l >> 4)*8 + jj;
        o[idx] = f2b(w[k*64 + n]);
    }
}

// ---------------------------------------------------------------------------
__global__ void k_hist(const int* __restrict__ eidx, const int* __restrict__ flags,
                       int* __restrict__ cnt) {
    int e = blockIdx.x * 256 + threadIdx.x;
    if (e >= NE) return;
    int is64 = flags[1];
    int r = eidx[is64 ? 2*(long)e : (long)e];
    atomicAdd(&cnt[r], 1);
}

__global__ __launch_bounds__(1024) void k_scan(const int* __restrict__ cnt,
                                               int* __restrict__ rowStart,
                                               int* __restrict__ cursor) {
    __shared__ int part[1024];
    int t = threadIdx.x;
    int base = t * 29;                    // NN == 1024*29
    int loc[29];
    int s = 0;
    #pragma unroll
    for (int i = 0; i < 29; ++i) { loc[i] = s; s += cnt[base + i]; }
    part[t] = s;
    __syncthreads();
    for (int d = 1; d < 1024; d <<= 1) {
        int v = (t >= d) ? part[t - d] : 0;
        __syncthreads();
        part[t] += v;
        __syncthreads();
    }
    int pre = (t == 0) ? 0 : part[t - 1];
    #pragma unroll
    for (int i = 0; i < 29; ++i) {
        int v = pre + loc[i];
        rowStart[base + i] = v;
        cursor[base + i] = v;
    }
    if (t == 1023) rowStart[NN] = pre + s;
}

__global__ void k_scatter(const int* __restrict__ eidx, const int* __restrict__ flags,
                          int* __restrict__ cursor,
                          int* __restrict__ rS, int* __restrict__ cS) {
    int e = blockIdx.x * 256 + threadIdx.x;
    if (e >= NE) return;
    int is64 = flags[1];
    long ge = e, gc = (long)e + NE;
    int r = eidx[is64 ? 2*ge : ge];
    int c = eidx[is64 ? 2*gc : gc];
    int p = atomicAdd(&cursor[r], 1);
    rS[p] = r; cS[p] = c;
}

// ---------------------------------------------------------------------------
__global__ void k_hz(const float* __restrict__ z, const float* __restrict__ lw,
                     const float* __restrict__ lb, float* __restrict__ hz) {
    __shared__ float zs[LAT];
    int b = blockIdx.x;
    int c = threadIdx.x;
    if (c < LAT) zs[c] = z[b*LAT + c];
    __syncthreads();
    float acc = lb[c];
    #pragma unroll
    for (int k = 0; k < LAT; ++k) acc += zs[k] * lw[k*HID + c];
    hz[b*HID + c] = acc;
}

// ---------------------------------------------------------------------------
// init3: h init (bf16) + pos init + zero agg/upd + H1(layer0) GEMM.
__global__ __launch_bounds__(256) void k_init3(
    const float* __restrict__ hz, const float* __restrict__ at,
    const float* __restrict__ aw, const float* __restrict__ ab,
    const float* __restrict__ ic,
    float* __restrict__ pos, short* __restrict__ hb,
    const short* __restrict__ wcat0, const float* __restrict__ b10,
    short* __restrict__ H1, float* __restrict__ agg, float* __restrict__ upd)
{
    __shared__ short x[64][136];
    __shared__ float awS[AF][HID];
    __shared__ float atS[64][AF+2];
    const int tid = threadIdx.x;
    const int n0 = blockIdx.x * 64;

    for (int i = tid; i < AF*HID; i += 256) awS[i/HID][i%HID] = aw[i];
    for (int i = tid; i < 64*AF; i += 256)
        atS[i/AF][i%AF] = at[(long)(n0 + i/AF)*AF + i%AF];
    __syncthreads();

    #pragma unroll
    for (int it = 0; it < 32; ++it) {
        int idx = it*256 + tid;
        int r = idx >> 7, c = idx & 127;
        int n = n0 + r;
        int bb = n / NA;
        float v = hz[bb*HID + c] + ab[c];
        #pragma unroll
        for (int f = 0; f < AF; ++f) v += atS[r][f]*awS[f][c];
        short s = f2b(v);
        x[r][c] = s;
        hb[(long)n*HID + c] = s;
    }
    if (tid < 192) {
        int i = tid/3, d = tid - i*3;
        int n = n0 + i;
        pos[n*3 + d] = ic[(n % NA)*3 + d];
        upd[n*3 + d] = 0.f;
    }
    {
        f4* a4 = (f4*)(agg + (long)n0*HID);
        for (int j = tid; j < 64*HID/4; j += 256) a4[j] = (f4)0.f;
    }
    __syncthreads();

    const int l = tid & 63, w = tid >> 6;
    const int l16 = l & 15, quad = l >> 4;
    f4 acc[4][4];
    #pragma unroll
    for (int mt = 0; mt < 4; ++mt)
        #pragma unroll
        for (int nt4 = 0; nt4 < 4; ++nt4) acc[mt][nt4] = (f4)0.f;
    #pragma unroll
    for (int kc = 0; kc < 4; ++kc) {
        s8 a[4];
        #pragma unroll
        for (int mt = 0; mt < 4; ++mt)
            a[mt] = *(const s8*)&x[mt*16 + l16][kc*32 + quad*8];
        #pragma unroll
        for (int nt4 = 0; nt4 < 4; ++nt4) {
            int nt = w*4 + nt4;
            s8 b = *(const s8*)(wcat0 + (((size_t)nt*4 + kc)*64 + l)*8);
            #pragma unroll
            for (int mt = 0; mt < 4; ++mt)
                acc[mt][nt4] = __builtin_amdgcn_mfma_f32_16x16x32_bf16(a[mt], b, acc[mt][nt4], 0, 0, 0);
        }
    }
    #pragma unroll
    for (int nt4 = 0; nt4 < 4; ++nt4) {
        int col = (w*4 + nt4)*16 + l16;
        float bias = (col < 128) ? b10[col] : 0.f;
        #pragma unroll
        for (int mt = 0; mt < 4; ++mt)
            #pragma unroll
            for (int i = 0; i < 4; ++i) {
                int row = mt*16 + quad*4 + i;
                H1[(long)(n0 + row)*256 + col] = f2b(acc[mt][nt4][i] + bias);
            }
    }
}

// ---------------------------------------------------------------------------
// Edge kernel v9: one wave = one 16-edge tile. ZERO block barriers in the loop.
// Stage2/3 B-frags re-loaded per tile (coalesced 1KB insts, L2-served);
// C->A layout hand-off via wave-private LDS scratch (lgkmcnt-ordered).
__global__ __launch_bounds__(256, 3) void k_edge9(
    const short* __restrict__ H1,
    const int* __restrict__ rS, const int* __restrict__ cS,
    const float* __restrict__ pos,
    const float* __restrict__ w1c,
    const short* __restrict__ w2p, const float* __restrict__ b2,
    const short* __restrict__ c1p, const float* __restrict__ cb1,
    const float* __restrict__ cw2,
    float* __restrict__ agg, float* __restrict__ upd)
{
    __shared__ short msc[4][16][136];   // per-wave m scratch (edge-major)
    __shared__ float cwS[4][16];

    const int tid = threadIdx.x;
    const int w = tid >> 6, l = tid & 63;
    const int l16 = l & 15, quad = l >> 4;

    // per-lane loop-invariant epilogue constants: col = nt*16 + l16, nt = 0..7
    float b2l[8], cbl[8], cwl[8];
    #pragma unroll
    for (int nt = 0; nt < 8; ++nt) {
        b2l[nt] = b2[nt*16 + l16];
        cbl[nt] = cb1[nt*16 + l16];
        cwl[nt] = cw2[nt*16 + l16];
    }

    for (int wt = blockIdx.x*4 + w; wt < NWT; wt += PBLK*4) {
        const long eb = (long)wt * 16;

        // ---- edge meta for this lane's A-row (edge l16)
        int r = rS[eb + l16], c = cS[eb + l16];
        float rx = pos[r*3+0] - pos[c*3+0];
        float ry = pos[r*3+1] - pos[c*3+1];
        float rz = pos[r*3+2] - pos[c*3+2];
        float d2 = fminf(fmaxf(rx*rx + ry*ry + rz*rz, 1e-6f), 1e6f);

        // ---- build t1 A-frags directly in registers
        s8 a[4];
        #pragma unroll
        for (int kc = 0; kc < 4; ++kc) {
            s8 va = *(const s8*)(H1 + (long)r*256 + kc*32 + quad*8);
            s8 vb = *(const s8*)(H1 + (long)c*256 + 128 + kc*32 + quad*8);
            f4 w0 = *(const f4*)(w1c + kc*32 + quad*8);
            f4 w1v = *(const f4*)(w1c + kc*32 + quad*8 + 4);
            s8 o;
            #pragma unroll
            for (int j = 0; j < 8; ++j) {
                float wvj = (j < 4) ? w0[j & 3] : w1v[j & 3];
                o[j] = f2b(siluf(b2f(va[j]) + b2f(vb[j]) + d2*wvj));
            }
            a[kc] = o;
        }

        // ---- stage 2: m = silu(t1 @ w2 + b2); write into msc (edge-major)
        #pragma unroll
        for (int nt = 0; nt < 8; ++nt) {
            f4 acc = (f4)0.f;
            #pragma unroll
            for (int kc = 0; kc < 4; ++kc) {
                s8 b = *(const s8*)(w2p + (((size_t)nt*4 + kc)*64 + l)*8);
                acc = __builtin_amdgcn_mfma_f32_16x16x32_bf16(a[kc], b, acc, 0, 0, 0);
            }
            int col = nt*16 + l16;
            #pragma unroll
            for (int i = 0; i < 4; ++i)
                msc[w][quad*4 + i][col] = f2b(siluf(acc[i] + b2l[nt]));
        }

        // ---- reload m as A-frags (wave-private, lgkmcnt-ordered)
        s8 ma[4];
        #pragma unroll
        for (int kc = 0; kc < 4; ++kc)
            ma[kc] = *(const s8*)&msc[w][l16][kc*32 + quad*8];

        // ---- stage 3: c1 = silu(m @ cw1 + cb1); dot cw2 -> per-row sums
        float accr[4] = {0.f, 0.f, 0.f, 0.f};
        #pragma unroll
        for (int nt = 0; nt < 8; ++nt) {
            f4 acc = (f4)0.f;
            #pragma unroll
            for (int kc = 0; kc < 4; ++kc) {
                s8 b = *(const s8*)(c1p + (((size_t)nt*4 + kc)*64 + l)*8);
                acc = __builtin_amdgcn_mfma_f32_16x16x32_bf16(ma[kc], b, acc, 0, 0, 0);
            }
            #pragma unroll
            for (int i = 0; i < 4; ++i)
                accr[i] += siluf(acc[i] + cbl[nt]) * cwl[nt];
        }
        #pragma unroll
        for (int i = 0; i < 4; ++i) {
            float p = accr[i];
            p += __shfl_xor(p, 1);
            p += __shfl_xor(p, 2);
            p += __shfl_xor(p, 4);
            p += __shfl_xor(p, 8);
            if (l16 == 0) cwS[w][quad*4 + i] = fminf(fmaxf(p, -1.f), 1.f);
        }

        // ---- agg: segmented sum over this tile's sorted 16 edges
        {
            float s0 = 0.f, s1 = 0.f;
            int cur = rS[eb];
            #pragma unroll
            for (int k = 0; k < 16; ++k) {
                int rr = rS[eb + k];
                if (rr != cur) {
                    atomicAdd(&agg[(long)cur*HID + l],      s0);
                    atomicAdd(&agg[(long)cur*HID + l + 64], s1);
                    s0 = 0.f; s1 = 0.f; cur = rr;
                }
                s0 += b2f(msc[w][k][l]);
                s1 += b2f(msc[w][k][l + 64]);
            }
            atomicAdd(&agg[(long)cur*HID + l],      s0);
            atomicAdd(&agg[(long)cur*HID + l + 64], s1);
        }

        // ---- upd
        if (l < 16) {
            float cwv = cwS[w][l];
            int rr = rS[eb + l], cc = cS[eb + l];
            float ux = pos[rr*3+0] - pos[cc*3+0];
            float uy = pos[rr*3+1] - pos[cc*3+1];
            float uz = pos[rr*3+2] - pos[cc*3+2];
            atomicAdd(&upd[rr*3+0], cwv*ux);
            atomicAdd(&upd[rr*3+1], cwv*uy);
            atomicAdd(&upd[rr*3+2], cwv*uz);
        }
    }
}

// ---------------------------------------------------------------------------
// Node kernel + fused H1(next layer) or fused head (last layer).
__global__ __launch_bounds__(256) void k_node_mfma(
    short* __restrict__ hb, float* __restrict__ agg,
    const short* __restrict__ w1p, const float* __restrict__ b1n,
    const short* __restrict__ w2p, const float* __restrict__ b2n,
    const float* __restrict__ lg, const float* __restrict__ lb,
    float* __restrict__ pos, float* __restrict__ upd,
    const int* __restrict__ rowStart,
    const short* __restrict__ wcatn, const float* __restrict__ b1next,
    short* __restrict__ H1,
    const short* __restrict__ hw1p, const float* __restrict__ hb1,
    const float* __restrict__ hw2, const float* __restrict__ hb2,
    void* __restrict__ out, const int* __restrict__ flags)
{
    __shared__ short x[64][264];
    __shared__ short t1[64][144];
    __shared__ float mus[64], rstds[64];
    __shared__ float posS[64][3];
    float (*hn)[132] = (float (*)[132])&x[0][0];
    float (*hid)[68] = (float (*)[68])&x[0][0];     // head scratch (alias, after hn dead)

    const int tid = threadIdx.x;
    const int n0 = blockIdx.x * 64;

    #pragma unroll
    for (int it = 0; it < 4; ++it) {
        int idx = it*256 + tid;
        int e = idx >> 4, qq = idx & 15;
        *(int4*)&x[e][qq*8] = *(const int4*)(hb + (long)(n0+e)*HID + qq*8);
    }
    #pragma unroll
    for (int it = 0; it < 8; ++it) {
        int idx = it*256 + tid;
        int e = idx >> 5, qq = idx & 31;
        float4 v = *(const float4*)(agg + (long)(n0+e)*HID + qq*4);
        short4 sv;
        sv.x = f2b(v.x); sv.y = f2b(v.y); sv.z = f2b(v.z); sv.w = f2b(v.w);
        *(short4*)&x[e][128 + qq*4] = sv;
    }
    __syncthreads();

    {
        f4* a4 = (f4*)(agg + (long)n0*HID);
        for (int j = tid; j < 64*HID/4; j += 256) a4[j] = (f4)0.f;
    }

    const int l = tid & 63, w = tid >> 6;
    const int l16 = l & 15, quad = l >> 4;
    const int nt0 = 2*w, nt1 = 2*w + 1;
    const int c0 = nt0*16 + l16, c1c = nt1*16 + l16;

    {
        f4 acc[4][2];
        #pragma unroll
        for (int mt = 0; mt < 4; ++mt) { acc[mt][0] = (f4)0.f; acc[mt][1] = (f4)0.f; }
        #pragma unroll
        for (int kc = 0; kc < 8; ++kc) {
            s8 b0  = *(const s8*)(w1p + (((size_t)nt0*8 + kc)*64 + l)*8);
            s8 b1f = *(const s8*)(w1p + (((size_t)nt1*8 + kc)*64 + l)*8);
            #pragma unroll
            for (int mt = 0; mt < 4; ++mt) {
                s8 a = *(const s8*)&x[mt*16 + l16][kc*32 + quad*8];
                acc[mt][0] = __builtin_amdgcn_mfma_f32_16x16x32_bf16(a, b0,  acc[mt][0], 0, 0, 0);
                acc[mt][1] = __builtin_amdgcn_mfma_f32_16x16x32_bf16(a, b1f, acc[mt][1], 0, 0, 0);
            }
        }
        float bia0 = b1n[c0], bia1 = b1n[c1c];
        #pragma unroll
        for (int mt = 0; mt < 4; ++mt) {
            #pragma unroll
            for (int i = 0; i < 4; ++i) {
                int row = mt*16 + quad*4 + i;
                t1[row][c0]  = f2b(siluf(acc[mt][0][i] + bia0));
                t1[row][c1c] = f2b(siluf(acc[mt][1][i] + bia1));
            }
        }
    }
    __syncthreads();

    {
        f4 acc[4][2];
        #pragma unroll
        for (int mt = 0; mt < 4; ++mt) { acc[mt][0] = (f4)0.f; acc[mt][1] = (f4)0.f; }
        #pragma unroll
        for (int kc = 0; kc < 4; ++kc) {
            s8 b0  = *(const s8*)(w2p + (((size_t)nt0*4 + kc)*64 + l)*8);
            s8 b1f = *(const s8*)(w2p + (((size_t)nt1*4 + kc)*64 + l)*8);
            #pragma unroll
            for (int mt = 0; mt < 4; ++mt) {
                s8 a = *(const s8*)&t1[mt*16 + l16][kc*32 + quad*8];
                acc[mt][0] = __builtin_amdgcn_mfma_f32_16x16x32_bf16(a, b0,  acc[mt][0], 0, 0, 0);
                acc[mt][1] = __builtin_amdgcn_mfma_f32_16x16x32_bf16(a, b1f, acc[mt][1], 0, 0, 0);
            }
        }
        float bia0 = b2n[c0], bia1 = b2n[c1c];
        __syncthreads();
        #pragma unroll
        for (int mt = 0; mt < 4; ++mt) {
            #pragma unroll
            for (int i = 0; i < 4; ++i) {
                int row = mt*16 + quad*4 + i;
                hn[row][c0]  = acc[mt][0][i] + bia0;
                hn[row][c1c] = acc[mt][1][i] + bia1;
            }
        }
    }
    __syncthreads();

    {
        int r = tid >> 2, part = tid & 3;
        float s = 0.f, qv = 0.f;
        #pragma unroll
        for (int j = 0; j < 32; ++j) {
            float v = hn[r][part + 4*j];
            s += v; qv += v*v;
        }
        s += __shfl_xor(s, 1); qv += __shfl_xor(qv, 1);
        s += __shfl_xor(s, 2); qv += __shfl_xor(qv, 2);
        if (part == 0) {
            float mu = s * (1.0f/HID);
            float var = qv * (1.0f/HID) - mu*mu;
            mus[r] = mu;
            rstds[r] = rsqrtf(var + 1e-5f);
        }
    }
    __syncthreads();

    #pragma unroll
    for (int it = 0; it < 32; ++it) {
        int idx = it*256 + tid;
        int r = idx >> 7, c = idx & 127;
        float v = (hn[r][c] - mus[r]) * rstds[r] * lg[c] + lb[c];
        short s = f2b(v);
        hb[(long)(n0 + r)*HID + c] = s;
        t1[r][c] = s;
    }
    if (tid < 192) {
        int i = tid / 3, d = tid - i*3;
        int n = n0 + i;
        float dg = (float)(rowStart[n+1] - rowStart[n]);
        float np = pos[n*3+d] + upd[n*3+d] / (dg + 1e-6f);
        pos[n*3+d] = np;
        posS[i][d] = np;
        upd[n*3+d] = 0.f;
    }
    __syncthreads();

    if (wcatn) {
        // H1 for next layer from staged t1
        f4 acc[4][4];
        #pragma unroll
        for (int mt = 0; mt < 4; ++mt)
            #pragma unroll
            for (int nt4 = 0; nt4 < 4; ++nt4) acc[mt][nt4] = (f4)0.f;
        #pragma unroll
        for (int kc = 0; kc < 4; ++kc) {
            s8 a[4];
            #pragma unroll
            for (int mt = 0; mt < 4; ++mt)
                a[mt] = *(const s8*)&t1[mt*16 + l16][kc*32 + quad*8];
            #pragma unroll
            for (int nt4 = 0; nt4 < 4; ++nt4) {
                int nt = w*4 + nt4;
                s8 b = *(const s8*)(wcatn + (((size_t)nt*4 + kc)*64 + l)*8);
                #pragma unroll
                for (int mt = 0; mt < 4; ++mt)
                    acc[mt][nt4] = __builtin_amdgcn_mfma_f32_16x16x32_bf16(a[mt], b, acc[mt][nt4], 0, 0, 0);
            }
        }
        #pragma unroll
        for (int nt4 = 0; nt4 < 4; ++nt4) {
            int col = (w*4 + nt4)*16 + l16;
            float bias = (col < 128) ? b1next[col] : 0.f;
            #pragma unroll
            for (int mt = 0; mt < 4; ++mt)
                #pragma unroll
                for (int i = 0; i < 4; ++i) {
                    int row = mt*16 + quad*4 + i;
                    H1[(long)(n0 + row)*256 + col] = f2b(acc[mt][nt4][i] + bias);
                }
        }
    } else {
        // fused head: hid = silu(h @ hw1 + hb1)  (N=64, wave w handles nt=w)
        f4 acc[4];
        #pragma unroll
        for (int mt = 0; mt < 4; ++mt) acc[mt] = (f4)0.f;
        #pragma unroll
        for (int kc = 0; kc < 4; ++kc) {
            s8 b = *(const s8*)(hw1p + (((size_t)w*4 + kc)*64 + l)*8);
            #pragma unroll
            for (int mt = 0; mt < 4; ++mt) {
                s8 a = *(const s8*)&t1[mt*16 + l16][kc*32 + quad*8];
                acc[mt] = __builtin_amdgcn_mfma_f32_16x16x32_bf16(a, b, acc[mt], 0, 0, 0);
            }
        }
        int col = w*16 + l16;
        float bias = hb1[col];
        #pragma unroll
        for (int mt = 0; mt < 4; ++mt)
            #pragma unroll
            for (int i = 0; i < 4; ++i) {
                int row = mt*16 + quad*4 + i;
                hid[row][col] = siluf(acc[mt][i] + bias);
            }
        __syncthreads();
        if (tid < 192) {
            int r = tid / 3, cc = tid - r*3;
            float a2 = hb2[cc];
            #pragma unroll
            for (int k = 0; k < 64; ++k) a2 += hid[r][k] * hw2[k*3 + cc];
            int n = n0 + r;
            float v = posS[r][cc] + a2;
            if (flags[0]) ((__hip_bfloat16*)out)[n*3+cc] = __float2bfloat16(v);
            else          ((float*)out)[n*3+cc] = v;
        }
    }
}

// ---------------------------------------------------------------------------
extern "C" void kernel_launch(void* const* d_in, const int* in_sizes, int n_in,
                              void* d_out, int out_size, void* d_ws, size_t ws_size,
                              hipStream_t stream)
{
    (void)in_sizes; (void)n_in; (void)out_size; (void)ws_size;

    int* flags = (int*)d_ws;
    float* base = (float*)d_ws;
    size_t off = 64;
    auto alloc = [&](size_t n) { float* p = base + off; off += (n + 63) & ~63ull; return p; };

    static const int aidx[24] = {0,1,3,4,5,6,7,8,9,10,11,12,13,14,15,16,17,18,19,20,21,22,23,24};
    static const int alen[24] = {
        BB*LAT, NN*AF, NA*3, LAT*HID, HID, AF*HID, HID,
        NL*257*HID, NL*HID, NL*HID*HID, NL*HID,
        NL*256*HID, NL*HID, NL*HID*HID, NL*HID,
        NL*HID*HID, NL*HID, NL*HID, NL*HID, NL*HID,
        HID*64, 64, 64*3, 3
    };
    CvtDesc cd;
    float* fp[24];
    for (int a = 0; a < 24; ++a) {
        fp[a] = alloc((size_t)alen[a]);
        cd.src[a] = d_in[aidx[a]];
        cd.dst[a] = fp[a];
        cd.len[a] = alen[a];
    }
    float* agg = alloc((size_t)NN*HID);
    float* hz  = alloc((size_t)BB*HID);
    float* pos = alloc((size_t)NN*3);
    float* upd = alloc((size_t)NN*3);
    short* hb  = (short*)alloc((size_t)NN*HID/2);
    short* H1  = (short*)alloc((size_t)NN*256/2);
    short* wcatp = (short*)alloc((size_t)NL*32768/2);
    short* w2p = (short*)alloc((size_t)NL*16384/2);
    short* c1p = (short*)alloc((size_t)NL*16384/2);
    short* nw1p = (short*)alloc((size_t)NL*32768/2);
    short* nw2p = (short*)alloc((size_t)NL*16384/2);
    short* hw1p = (short*)alloc((size_t)8192/2);
    int* cnt      = (int*)alloc((size_t)NN);
    int* rowStart = (int*)alloc((size_t)NN + 1);
    int* cursor   = (int*)alloc((size_t)NN);
    int* rS       = (int*)alloc((size_t)NE);
    int* cS       = (int*)alloc((size_t)NE);
    const int* eidx = (const int*)d_in[2];

    k_detect<<<1, 256, 0, stream>>>((const unsigned short*)d_in[0],
                                    (const unsigned int*)d_in[2], flags);
    k_convert<<<dim3((NN*AF + 255)/256, 24), 256, 0, stream>>>(cd, flags);

    PackJobs pj;
    for (int l = 0; l < NL; ++l) {
        int b5 = l*5;
        pj.src[b5+0] = fp[7]  + (size_t)l*257*HID; pj.dst[b5+0] = wcatp + (size_t)l*32768; pj.K[b5+0] = 256; pj.mode[b5+0] = 1;
        pj.src[b5+1] = fp[9]  + (size_t)l*HID*HID; pj.dst[b5+1] = w2p   + (size_t)l*16384; pj.K[b5+1] = 128; pj.mode[b5+1] = 0;
        pj.src[b5+2] = fp[15] + (size_t)l*HID*HID; pj.dst[b5+2] = c1p   + (size_t)l*16384; pj.K[b5+2] = 128; pj.mode[b5+2] = 0;
        pj.src[b5+3] = fp[11] + (size_t)l*256*HID; pj.dst[b5+3] = nw1p  + (size_t)l*32768; pj.K[b5+3] = 256; pj.mode[b5+3] = 0;
        pj.src[b5+4] = fp[13] + (size_t)l*HID*HID; pj.dst[b5+4] = nw2p  + (size_t)l*16384; pj.K[b5+4] = 128; pj.mode[b5+4] = 0;
    }
    pj.src[10] = fp[20]; pj.dst[10] = hw1p; pj.K[10] = 128; pj.mode[10] = 2;
    k_packall<<<dim3(128, 11), 256, 0, stream>>>(pj);

    // counting sort edges by row
    hipMemsetAsync(cnt, 0, (size_t)NN*sizeof(int), stream);
    k_hist<<<(NE + 255)/256, 256, 0, stream>>>(eidx, flags, cnt);
    k_scan<<<1, 1024, 0, stream>>>(cnt, rowStart, cursor);
    k_scatter<<<(NE + 255)/256, 256, 0, stream>>>(eidx, flags, cursor, rS, cS);

    k_hz<<<BB, HID, 0, stream>>>(fp[0], fp[3], fp[4], hz);
    k_init3<<<NN/64, 256, 0, stream>>>(hz, fp[1], fp[5], fp[6], fp[2], pos, hb,
                                       wcatp, fp[8], H1, agg, upd);

    for (int l = 0; l < NL; ++l) {
        k_edge9<<<PBLK, 256, 0, stream>>>(H1, rS, cS, pos,
            fp[7] + (size_t)l*257*HID + 256*HID,       // w1c (d2 row, f32)
            w2p + (size_t)l*16384, fp[10] + (size_t)l*HID,
            c1p + (size_t)l*16384, fp[16] + (size_t)l*HID,
            fp[17] + (size_t)l*HID,
            agg, upd);
        const short* wcatn = (l+1 < NL) ? (wcatp + (size_t)(l+1)*32768) : nullptr;
        const float* b1nx  = (l+1 < NL) ? (fp[8] + (size_t)(l+1)*HID) : fp[8];
        k_node_mfma<<<NN/64, 256, 0, stream>>>(hb, agg,
            nw1p + (size_t)l*32768, fp[12] + (size_t)l*HID,
            nw2p + (size_t)l*16384, fp[14] + (size_t)l*HID,
            fp[18] + (size_t)l*HID, fp[19] + (size_t)l*HID,
            pos, upd, rowStart, wcatn, b1nx, H1,
            hw1p, fp[21], fp[22], fp[23], d_out, flags);
    }
}

// Round 14
// 606.892 us; speedup vs baseline: 1.8093x; 1.8093x over previous
//
#include <hip/hip_runtime.h>
#include <hip/hip_bf16.h>

#define BB 512
#define NA 58
#define LAT 64
#define HID 128
#define AF 10
#define NL 2
#define NN (BB*NA)      // 29696
#define NE (NN*16)      // 475136
#define ET 64           // edges per tile
#define NTILE (NE/ET)   // 7424
#define PBLK 768        // persistent blocks

typedef __attribute__((ext_vector_type(8))) short s8;
typedef __attribute__((ext_vector_type(4))) float f4;

struct CvtDesc {
    const void* src[24];
    float*      dst[24];
    int         len[24];
};

struct PackJobs {
    const float* src[11];
    short*       dst[11];
    int          K[11];
    int          mode[11];   // 0: [K][128] B-frag; 1: edge-w1 concat; 2: [K][64] B-frag
};

__device__ __forceinline__ float siluf(float x) {
    return x * __builtin_amdgcn_rcpf(1.0f + __expf(-x));
}

__device__ __forceinline__ short f2b(float x) {
    __hip_bfloat16 b = __float2bfloat16(x);
    return *(short*)&b;
}

__device__ __forceinline__ float b2f(short s) {
    return __uint_as_float(((unsigned int)(unsigned short)s) << 16);
}

// ---------------------------------------------------------------------------
__global__ void k_detect(const unsigned short* __restrict__ z16,
                         const unsigned int* __restrict__ e32,
                         int* __restrict__ flags) {
    __shared__ int sbf, si64;
    if (threadIdx.x == 0) { sbf = 0; si64 = 0; }
    __syncthreads();
    int c1 = 0, c2 = 0;
    for (int i = threadIdx.x; i < 1024; i += 256) {
        unsigned short v = z16[2*i];
        int e = (v >> 7) & 0xFF;
        if (e >= 100 && e <= 140) c1++;
        if (e32[2*i + 1] == 0u) c2++;
    }
    atomicAdd(&sbf, c1);
    atomicAdd(&si64, c2);
    __syncthreads();
    if (threadIdx.x == 0) {
        flags[0] = (sbf  > 600) ? 1 : 0;
        flags[1] = (si64 > 600) ? 1 : 0;
    }
}

__global__ void k_convert(CvtDesc d, const int* __restrict__ flags) {
    int a = blockIdx.y;
    int i = blockIdx.x * blockDim.x + threadIdx.x;
    int n = d.len[a];
    if (i >= n) return;
    if (flags[0]) {
        d.dst[a][i] = __bfloat162float(((const __hip_bfloat16*)d.src[a])[i]);
    } else {
        d.dst[a][i] = ((const float*)d.src[a])[i];
    }
}

__global__ void k_packall(PackJobs pj) {
    int j = blockIdx.y;
    int idx = blockIdx.x * 256 + threadIdx.x;
    const float* w = pj.src[j];
    short* o = pj.dst[j];
    int mode = pj.mode[j];
    if (mode == 0) {
        int K = pj.K[j];
        if (idx >= 128*K) return;
        int jj = idx & 7;
        int l  = (idx >> 3) & 63;
        int rest = idx >> 9;
        int KC = K >> 5;
        int kc = rest % KC;
        int nt = rest / KC;
        int n = nt*16 + (l & 15);
        int k = kc*32 + (l >> 4)*8 + jj;
        o[idx] = f2b(w[k*128 + n]);
    } else if (mode == 1) {
        if (idx >= 32768) return;
        int jj = idx & 7;
        int l  = (idx >> 3) & 63;
        int rest = idx >> 9;
        int kc = rest & 3;
        int nt = rest >> 2;
        int n = nt*16 + (l & 15);
        int k = kc*32 + (l >> 4)*8 + jj;
        float v = (n < 128) ? w[k*128 + n] : w[(128 + k)*128 + (n - 128)];
        o[idx] = f2b(v);
    } else {
        if (idx >= 8192) return;
        int jj = idx & 7;
        int l  = (idx >> 3) & 63;
        int rest = idx >> 9;
        int kc = rest & 3;
        int nt = rest >> 2;
        int n = nt*16 + (l & 15);
        int k = kc*32 + (l >> 4)*8 + jj;
        o[idx] = f2b(w[k*64 + n]);
    }
}

// ---------------------------------------------------------------------------
__global__ void k_hist(const int* __restrict__ eidx, const int* __restrict__ flags,
                       int* __restrict__ cnt) {
    int e = blockIdx.x * 256 + threadIdx.x;
    if (e >= NE) return;
    int is64 = flags[1];
    int r = eidx[is64 ? 2*(long)e : (long)e];
    atomicAdd(&cnt[r], 1);
}

__global__ __launch_bounds__(1024) void k_scan(const int* __restrict__ cnt,
                                               int* __restrict__ rowStart,
                                               int* __restrict__ cursor) {
    __shared__ int part[1024];
    int t = threadIdx.x;
    int base = t * 29;                    // NN == 1024*29
    int loc[29];
    int s = 0;
    #pragma unroll
    for (int i = 0; i < 29; ++i) { loc[i] = s; s += cnt[base + i]; }
    part[t] = s;
    __syncthreads();
    for (int d = 1; d < 1024; d <<= 1) {
        int v = (t >= d) ? part[t - d] : 0;
        __syncthreads();
        part[t] += v;
        __syncthreads();
    }
    int pre = (t == 0) ? 0 : part[t - 1];
    #pragma unroll
    for (int i = 0; i < 29; ++i) {
        int v = pre + loc[i];
        rowStart[base + i] = v;
        cursor[base + i] = v;
    }
    if (t == 1023) rowStart[NN] = pre + s;
}

__global__ void k_scatter(const int* __restrict__ eidx, const int* __restrict__ flags,
                          int* __restrict__ cursor,
                          int* __restrict__ rS, int* __restrict__ cS) {
    int e = blockIdx.x * 256 + threadIdx.x;
    if (e >= NE) return;
    int is64 = flags[1];
    long ge = e, gc = (long)e + NE;
    int r = eidx[is64 ? 2*ge : ge];
    int c = eidx[is64 ? 2*gc : gc];
    int p = atomicAdd(&cursor[r], 1);
    rS[p] = r; cS[p] = c;
}

// ---------------------------------------------------------------------------
__global__ void k_hz(const float* __restrict__ z, const float* __restrict__ lw,
                     const float* __restrict__ lb, float* __restrict__ hz) {
    __shared__ float zs[LAT];
    int b = blockIdx.x;
    int c = threadIdx.x;
    if (c < LAT) zs[c] = z[b*LAT + c];
    __syncthreads();
    float acc = lb[c];
    #pragma unroll
    for (int k = 0; k < LAT; ++k) acc += zs[k] * lw[k*HID + c];
    hz[b*HID + c] = acc;
}

// ---------------------------------------------------------------------------
// init3: h init (bf16) + pos init + zero agg/upd + H1(layer0) GEMM.
__global__ __launch_bounds__(256) void k_init3(
    const float* __restrict__ hz, const float* __restrict__ at,
    const float* __restrict__ aw, const float* __restrict__ ab,
    const float* __restrict__ ic,
    float* __restrict__ pos, short* __restrict__ hb,
    const short* __restrict__ wcat0, const float* __restrict__ b10,
    short* __restrict__ H1, float* __restrict__ agg, float* __restrict__ upd)
{
    __shared__ short x[64][136];
    __shared__ float awS[AF][HID];
    __shared__ float atS[64][AF+2];
    const int tid = threadIdx.x;
    const int n0 = blockIdx.x * 64;

    for (int i = tid; i < AF*HID; i += 256) awS[i/HID][i%HID] = aw[i];
    for (int i = tid; i < 64*AF; i += 256)
        atS[i/AF][i%AF] = at[(long)(n0 + i/AF)*AF + i%AF];
    __syncthreads();

    #pragma unroll
    for (int it = 0; it < 32; ++it) {
        int idx = it*256 + tid;
        int r = idx >> 7, c = idx & 127;
        int n = n0 + r;
        int bb = n / NA;
        float v = hz[bb*HID + c] + ab[c];
        #pragma unroll
        for (int f = 0; f < AF; ++f) v += atS[r][f]*awS[f][c];
        short s = f2b(v);
        x[r][c] = s;
        hb[(long)n*HID + c] = s;
    }
    if (tid < 192) {
        int i = tid/3, d = tid - i*3;
        int n = n0 + i;
        pos[n*3 + d] = ic[(n % NA)*3 + d];
        upd[n*3 + d] = 0.f;
    }
    {
        f4* a4 = (f4*)(agg + (long)n0*HID);
        for (int j = tid; j < 64*HID/4; j += 256) a4[j] = (f4)0.f;
    }
    __syncthreads();

    const int l = tid & 63, w = tid >> 6;
    const int l16 = l & 15, quad = l >> 4;
    f4 acc[4][4];
    #pragma unroll
    for (int mt = 0; mt < 4; ++mt)
        #pragma unroll
        for (int nt4 = 0; nt4 < 4; ++nt4) acc[mt][nt4] = (f4)0.f;
    #pragma unroll
    for (int kc = 0; kc < 4; ++kc) {
        s8 a[4];
        #pragma unroll
        for (int mt = 0; mt < 4; ++mt)
            a[mt] = *(const s8*)&x[mt*16 + l16][kc*32 + quad*8];
        #pragma unroll
        for (int nt4 = 0; nt4 < 4; ++nt4) {
            int nt = w*4 + nt4;
            s8 b = *(const s8*)(wcat0 + (((size_t)nt*4 + kc)*64 + l)*8);
            #pragma unroll
            for (int mt = 0; mt < 4; ++mt)
                acc[mt][nt4] = __builtin_amdgcn_mfma_f32_16x16x32_bf16(a[mt], b, acc[mt][nt4], 0, 0, 0);
        }
    }
    #pragma unroll
    for (int nt4 = 0; nt4 < 4; ++nt4) {
        int col = (w*4 + nt4)*16 + l16;
        float bias = (col < 128) ? b10[col] : 0.f;
        #pragma unroll
        for (int mt = 0; mt < 4; ++mt)
            #pragma unroll
            for (int i = 0; i < 4; ++i) {
                int row = mt*16 + quad*4 + i;
                H1[(long)(n0 + row)*256 + col] = f2b(acc[mt][nt4][i] + bias);
            }
    }
}

// ---------------------------------------------------------------------------
// Edge kernel v8 (R12, proven): double-buffered t1, 2 barriers/tile, gathers
// for tile T+1 interleaved with stage2 MFMA of tile T; weights in registers.
__global__ __launch_bounds__(256, 3) void k_edge8(
    const short* __restrict__ H1,
    const int* __restrict__ rS, const int* __restrict__ cS,
    const float* __restrict__ pos,
    const float* __restrict__ w1c,
    const short* __restrict__ w2p, const float* __restrict__ b2,
    const short* __restrict__ c1p, const float* __restrict__ cb1,
    const float* __restrict__ cw2,
    float* __restrict__ agg, float* __restrict__ upd)
{
    __shared__ short t1[2][ET][136];
    __shared__ short mm[ET][136];
    __shared__ int   rIs[2][ET], cIs[2][ET];
    __shared__ float sred[ET];

    const int tid = threadIdx.x;
    const int l = tid & 63, w = tid >> 6;
    const int l16 = l & 15, quad = l >> 4;
    const int c0 = (2*w)*16 + l16, c1c = (2*w+1)*16 + l16;
    const int half = tid >> 7, ch = tid & 127;
    const int q = tid & 15;
    const int esub = tid >> 4;

    float wv[8];
    #pragma unroll
    for (int j = 0; j < 8; ++j) wv[j] = w1c[q*8 + j];

    s8 w2f[8], c1f[8];
    #pragma unroll
    for (int kc = 0; kc < 4; ++kc) {
        w2f[kc]     = *(const s8*)(w2p + (((size_t)(2*w)*4 + kc)*64 + l)*8);
        w2f[4 + kc] = *(const s8*)(w2p + (((size_t)(2*w+1)*4 + kc)*64 + l)*8);
        c1f[kc]     = *(const s8*)(c1p + (((size_t)(2*w)*4 + kc)*64 + l)*8);
        c1f[4 + kc] = *(const s8*)(c1p + (((size_t)(2*w+1)*4 + kc)*64 + l)*8);
    }
    const float bia2_0 = b2[c0],  bia2_1 = b2[c1c];
    const float biac_0 = cb1[c0], biac_1 = cb1[c1c];
    const float cw0    = cw2[c0], cw1v   = cw2[c1c];

    int   pri[4], pci[4];
    float pd2[4];
    auto PREIDX = [&](int T) {
        long eb = (long)T * ET;
        #pragma unroll
        for (int it = 0; it < 4; ++it) {
            int e = esub + 16*it;
            int r = rS[eb + e], c = cS[eb + e];
            pri[it] = r; pci[it] = c;
            float rx = pos[r*3+0] - pos[c*3+0];
            float ry = pos[r*3+1] - pos[c*3+1];
            float rz = pos[r*3+2] - pos[c*3+2];
            pd2[it] = fminf(fmaxf(rx*rx + ry*ry + rz*rz, 1e-6f), 1e6f);
        }
    };

    // prologue: build tile T into t1[0]
    int T = blockIdx.x;
    PREIDX(T);
    #pragma unroll
    for (int it = 0; it < 4; ++it) {
        s8 va = *(const s8*)(H1 + (long)pri[it]*256 + q*8);
        s8 vb = *(const s8*)(H1 + (long)pci[it]*256 + 128 + q*8);
        float d2 = pd2[it];
        s8 o;
        #pragma unroll
        for (int j = 0; j < 8; ++j)
            o[j] = f2b(siluf(b2f(va[j]) + b2f(vb[j]) + d2*wv[j]));
        *(s8*)&t1[0][esub + 16*it][q*8] = o;
    }
    if (q == 0) {
        #pragma unroll
        for (int it = 0; it < 4; ++it) {
            rIs[0][esub + 16*it] = pri[it];
            cIs[0][esub + 16*it] = pci[it];
        }
    }
    if (tid < ET) sred[tid] = 0.f;
    int Tn = T + PBLK;
    if (Tn < NTILE) PREIDX(Tn);
    __syncthreads();

    int b = 0;
    while (true) {
        const bool hasNext = (Tn < NTILE);

        // half1: stage2(T) from t1[b] ⊗ build t1[b^1](Tn)
        {
            f4 acc[4][2];
            #pragma unroll
            for (int mt = 0; mt < 4; ++mt) { acc[mt][0] = (f4)0.f; acc[mt][1] = (f4)0.f; }
            #pragma unroll
            for (int it = 0; it < 4; ++it) {
                s8 va, vb;
                if (hasNext) {
                    va = *(const s8*)(H1 + (long)pri[it]*256 + q*8);
                    vb = *(const s8*)(H1 + (long)pci[it]*256 + 128 + q*8);
                }
                #pragma unroll
                for (int mt = 0; mt < 4; ++mt) {
                    s8 a = *(const s8*)&t1[b][mt*16 + l16][it*32 + quad*8];
                    acc[mt][0] = __builtin_amdgcn_mfma_f32_16x16x32_bf16(a, w2f[it],     acc[mt][0], 0, 0, 0);
                    acc[mt][1] = __builtin_amdgcn_mfma_f32_16x16x32_bf16(a, w2f[4 + it], acc[mt][1], 0, 0, 0);
                }
                if (hasNext) {
                    float d2 = pd2[it];
                    s8 o;
                    #pragma unroll
                    for (int j = 0; j < 8; ++j)
                        o[j] = f2b(siluf(b2f(va[j]) + b2f(vb[j]) + d2*wv[j]));
                    *(s8*)&t1[b^1][esub + 16*it][q*8] = o;
                }
            }
            if (hasNext && q == 0) {
                #pragma unroll
                for (int it = 0; it < 4; ++it) {
                    rIs[b^1][esub + 16*it] = pri[it];
                    cIs[b^1][esub + 16*it] = pci[it];
                }
            }
            #pragma unroll
            for (int mt = 0; mt < 4; ++mt) {
                #pragma unroll
                for (int i = 0; i < 4; ++i) {
                    int row = mt*16 + quad*4 + i;
                    mm[row][c0]  = f2b(siluf(acc[mt][0][i] + bia2_0));
                    mm[row][c1c] = f2b(siluf(acc[mt][1][i] + bia2_1));
                }
            }
        }
        __syncthreads();                 // (1)

        // half2: stage3(T) + agg(T) + PREIDX(T+2)
        {
            f4 acc[4][2];
            #pragma unroll
            for (int mt = 0; mt < 4; ++mt) { acc[mt][0] = (f4)0.f; acc[mt][1] = (f4)0.f; }
            #pragma unroll
            for (int kc = 0; kc < 4; ++kc) {
                #pragma unroll
                for (int mt = 0; mt < 4; ++mt) {
                    s8 a = *(const s8*)&mm[mt*16 + l16][kc*32 + quad*8];
                    acc[mt][0] = __builtin_amdgcn_mfma_f32_16x16x32_bf16(a, c1f[kc],     acc[mt][0], 0, 0, 0);
                    acc[mt][1] = __builtin_amdgcn_mfma_f32_16x16x32_bf16(a, c1f[4 + kc], acc[mt][1], 0, 0, 0);
                }
            }
            #pragma unroll
            for (int mt = 0; mt < 4; ++mt) {
                #pragma unroll
                for (int i = 0; i < 4; ++i) {
                    float p = siluf(acc[mt][0][i] + biac_0) * cw0
                            + siluf(acc[mt][1][i] + biac_1) * cw1v;
                    p += __shfl_xor(p, 1);
                    p += __shfl_xor(p, 2);
                    p += __shfl_xor(p, 4);
                    p += __shfl_xor(p, 8);
                    if (l16 == 0) {
                        int row = mt*16 + quad*4 + i;
                        atomicAdd(&sred[row], p);
                    }
                }
            }
        }
        {
            int e0 = half * 32;
            int cur = rIs[b][e0];
            float a = 0.f;
            #pragma unroll
            for (int e = e0; e < e0 + 32; ++e) {
                int r = rIs[b][e];
                if (r != cur) {
                    atomicAdd(&agg[(long)cur*HID + ch], a);
                    a = 0.f; cur = r;
                }
                a += b2f(mm[e][ch]);
            }
            atomicAdd(&agg[(long)cur*HID + ch], a);
        }
        int Tnn = Tn + PBLK;
        if (hasNext && Tnn < NTILE) PREIDX(Tnn);
        __syncthreads();                 // (2)

        if (tid < ET) {
            float cwv = fminf(fmaxf(sred[tid], -1.f), 1.f);
            sred[tid] = 0.f;
            int r = rIs[b][tid], c = cIs[b][tid];
            float rx = pos[r*3+0] - pos[c*3+0];
            float ry = pos[r*3+1] - pos[c*3+1];
            float rz = pos[r*3+2] - pos[c*3+2];
            atomicAdd(&upd[r*3+0], cwv*rx);
            atomicAdd(&upd[r*3+1], cwv*ry);
            atomicAdd(&upd[r*3+2], cwv*rz);
        }
        if (!hasNext) break;
        T = Tn; Tn = Tnn; b ^= 1;
    }
}

// ---------------------------------------------------------------------------
// Node kernel + fused H1(next layer) or fused head (last layer).
__global__ __launch_bounds__(256) void k_node_mfma(
    short* __restrict__ hb, float* __restrict__ agg,
    const short* __restrict__ w1p, const float* __restrict__ b1n,
    const short* __restrict__ w2p, const float* __restrict__ b2n,
    const float* __restrict__ lg, const float* __restrict__ lb,
    float* __restrict__ pos, float* __restrict__ upd,
    const int* __restrict__ rowStart,
    const short* __restrict__ wcatn, const float* __restrict__ b1next,
    short* __restrict__ H1,
    const short* __restrict__ hw1p, const float* __restrict__ hb1,
    const float* __restrict__ hw2, const float* __restrict__ hb2,
    void* __restrict__ out, const int* __restrict__ flags)
{
    __shared__ short x[64][264];
    __shared__ short t1[64][144];
    __shared__ float mus[64], rstds[64];
    __shared__ float posS[64][3];
    float (*hn)[132] = (float (*)[132])&x[0][0];
    float (*hid)[68] = (float (*)[68])&x[0][0];

    const int tid = threadIdx.x;
    const int n0 = blockIdx.x * 64;

    #pragma unroll
    for (int it = 0; it < 4; ++it) {
        int idx = it*256 + tid;
        int e = idx >> 4, qq = idx & 15;
        *(int4*)&x[e][qq*8] = *(const int4*)(hb + (long)(n0+e)*HID + qq*8);
    }
    #pragma unroll
    for (int it = 0; it < 8; ++it) {
        int idx = it*256 + tid;
        int e = idx >> 5, qq = idx & 31;
        float4 v = *(const float4*)(agg + (long)(n0+e)*HID + qq*4);
        short4 sv;
        sv.x = f2b(v.x); sv.y = f2b(v.y); sv.z = f2b(v.z); sv.w = f2b(v.w);
        *(short4*)&x[e][128 + qq*4] = sv;
    }
    __syncthreads();

    {
        f4* a4 = (f4*)(agg + (long)n0*HID);
        for (int j = tid; j < 64*HID/4; j += 256) a4[j] = (f4)0.f;
    }

    const int l = tid & 63, w = tid >> 6;
    const int l16 = l & 15, quad = l >> 4;
    const int nt0 = 2*w, nt1 = 2*w + 1;
    const int c0 = nt0*16 + l16, c1c = nt1*16 + l16;

    {
        f4 acc[4][2];
        #pragma unroll
        for (int mt = 0; mt < 4; ++mt) { acc[mt][0] = (f4)0.f; acc[mt][1] = (f4)0.f; }
        #pragma unroll
        for (int kc = 0; kc < 8; ++kc) {
            s8 b0  = *(const s8*)(w1p + (((size_t)nt0*8 + kc)*64 + l)*8);
            s8 b1f = *(const s8*)(w1p + (((size_t)nt1*8 + kc)*64 + l)*8);
            #pragma unroll
            for (int mt = 0; mt < 4; ++mt) {
                s8 a = *(const s8*)&x[mt*16 + l16][kc*32 + quad*8];
                acc[mt][0] = __builtin_amdgcn_mfma_f32_16x16x32_bf16(a, b0,  acc[mt][0], 0, 0, 0);
                acc[mt][1] = __builtin_amdgcn_mfma_f32_16x16x32_bf16(a, b1f, acc[mt][1], 0, 0, 0);
            }
        }
        float bia0 = b1n[c0], bia1 = b1n[c1c];
        #pragma unroll
        for (int mt = 0; mt < 4; ++mt) {
            #pragma unroll
            for (int i = 0; i < 4; ++i) {
                int row = mt*16 + quad*4 + i;
                t1[row][c0]  = f2b(siluf(acc[mt][0][i] + bia0));
                t1[row][c1c] = f2b(siluf(acc[mt][1][i] + bia1));
            }
        }
    }
    __syncthreads();

    {
        f4 acc[4][2];
        #pragma unroll
        for (int mt = 0; mt < 4; ++mt) { acc[mt][0] = (f4)0.f; acc[mt][1] = (f4)0.f; }
        #pragma unroll
        for (int kc = 0; kc < 4; ++kc) {
            s8 b0  = *(const s8*)(w2p + (((size_t)nt0*4 + kc)*64 + l)*8);
            s8 b1f = *(const s8*)(w2p + (((size_t)nt1*4 + kc)*64 + l)*8);
            #pragma unroll
            for (int mt = 0; mt < 4; ++mt) {
                s8 a = *(const s8*)&t1[mt*16 + l16][kc*32 + quad*8];
                acc[mt][0] = __builtin_amdgcn_mfma_f32_16x16x32_bf16(a, b0,  acc[mt][0], 0, 0, 0);
                acc[mt][1] = __builtin_amdgcn_mfma_f32_16x16x32_bf16(a, b1f, acc[mt][1], 0, 0, 0);
            }
        }
        float bia0 = b2n[c0], bia1 = b2n[c1c];
        __syncthreads();
        #pragma unroll
        for (int mt = 0; mt < 4; ++mt) {
            #pragma unroll
            for (int i = 0; i < 4; ++i) {
                int row = mt*16 + quad*4 + i;
                hn[row][c0]  = acc[mt][0][i] + bia0;
                hn[row][c1c] = acc[mt][1][i] + bia1;
            }
        }
    }
    __syncthreads();

    {
        int r = tid >> 2, part = tid & 3;
        float s = 0.f, qv = 0.f;
        #pragma unroll
        for (int j = 0; j < 32; ++j) {
            float v = hn[r][part + 4*j];
            s += v; qv += v*v;
        }
        s += __shfl_xor(s, 1); qv += __shfl_xor(qv, 1);
        s += __shfl_xor(s, 2); qv += __shfl_xor(qv, 2);
        if (part == 0) {
            float mu = s * (1.0f/HID);
            float var = qv * (1.0f/HID) - mu*mu;
            mus[r] = mu;
            rstds[r] = rsqrtf(var + 1e-5f);
        }
    }
    __syncthreads();

    #pragma unroll
    for (int it = 0; it < 32; ++it) {
        int idx = it*256 + tid;
        int r = idx >> 7, c = idx & 127;
        float v = (hn[r][c] - mus[r]) * rstds[r] * lg[c] + lb[c];
        short s = f2b(v);
        hb[(long)(n0 + r)*HID + c] = s;
        t1[r][c] = s;
    }
    if (tid < 192) {
        int i = tid / 3, d = tid - i*3;
        int n = n0 + i;
        float dg = (float)(rowStart[n+1] - rowStart[n]);
        float np = pos[n*3+d] + upd[n*3+d] / (dg + 1e-6f);
        pos[n*3+d] = np;
        posS[i][d] = np;
        upd[n*3+d] = 0.f;
    }
    __syncthreads();

    if (wcatn) {
        f4 acc[4][4];
        #pragma unroll
        for (int mt = 0; mt < 4; ++mt)
            #pragma unroll
            for (int nt4 = 0; nt4 < 4; ++nt4) acc[mt][nt4] = (f4)0.f;
        #pragma unroll
        for (int kc = 0; kc < 4; ++kc) {
            s8 a[4];
            #pragma unroll
            for (int mt = 0; mt < 4; ++mt)
                a[mt] = *(const s8*)&t1[mt*16 + l16][kc*32 + quad*8];
            #pragma unroll
            for (int nt4 = 0; nt4 < 4; ++nt4) {
                int nt = w*4 + nt4;
                s8 b = *(const s8*)(wcatn + (((size_t)nt*4 + kc)*64 + l)*8);
                #pragma unroll
                for (int mt = 0; mt < 4; ++mt)
                    acc[mt][nt4] = __builtin_amdgcn_mfma_f32_16x16x32_bf16(a[mt], b, acc[mt][nt4], 0, 0, 0);
            }
        }
        #pragma unroll
        for (int nt4 = 0; nt4 < 4; ++nt4) {
            int col = (w*4 + nt4)*16 + l16;
            float bias = (col < 128) ? b1next[col] : 0.f;
            #pragma unroll
            for (int mt = 0; mt < 4; ++mt)
                #pragma unroll
                for (int i = 0; i < 4; ++i) {
                    int row = mt*16 + quad*4 + i;
                    H1[(long)(n0 + row)*256 + col] = f2b(acc[mt][nt4][i] + bias);
                }
        }
    } else {
        f4 acc[4];
        #pragma unroll
        for (int mt = 0; mt < 4; ++mt) acc[mt] = (f4)0.f;
        #pragma unroll
        for (int kc = 0; kc < 4; ++kc) {
            s8 b = *(const s8*)(hw1p + (((size_t)w*4 + kc)*64 + l)*8);
            #pragma unroll
            for (int mt = 0; mt < 4; ++mt) {
                s8 a = *(const s8*)&t1[mt*16 + l16][kc*32 + quad*8];
                acc[mt] = __builtin_amdgcn_mfma_f32_16x16x32_bf16(a, b, acc[mt], 0, 0, 0);
            }
        }
        int col = w*16 + l16;
        float bias = hb1[col];
        #pragma unroll
        for (int mt = 0; mt < 4; ++mt)
            #pragma unroll
            for (int i = 0; i < 4; ++i) {
                int row = mt*16 + quad*4 + i;
                hid[row][col] = siluf(acc[mt][i] + bias);
            }
        __syncthreads();
        if (tid < 192) {
            int r = tid / 3, cc = tid - r*3;
            float a2 = hb2[cc];
            #pragma unroll
            for (int k = 0; k < 64; ++k) a2 += hid[r][k] * hw2[k*3 + cc];
            int n = n0 + r;
            float v = posS[r][cc] + a2;
            if (flags[0]) ((__hip_bfloat16*)out)[n*3+cc] = __float2bfloat16(v);
            else          ((float*)out)[n*3+cc] = v;
        }
    }
}

// ---------------------------------------------------------------------------
extern "C" void kernel_launch(void* const* d_in, const int* in_sizes, int n_in,
                              void* d_out, int out_size, void* d_ws, size_t ws_size,
                              hipStream_t stream)
{
    (void)in_sizes; (void)n_in; (void)out_size; (void)ws_size;

    int* flags = (int*)d_ws;
    float* base = (float*)d_ws;
    size_t off = 64;
    auto alloc = [&](size_t n) { float* p = base + off; off += (n + 63) & ~63ull; return p; };

    static const int aidx[24] = {0,1,3,4,5,6,7,8,9,10,11,12,13,14,15,16,17,18,19,20,21,22,23,24};
    static const int alen[24] = {
        BB*LAT, NN*AF, NA*3, LAT*HID, HID, AF*HID, HID,
        NL*257*HID, NL*HID, NL*HID*HID, NL*HID,
        NL*256*HID, NL*HID, NL*HID*HID, NL*HID,
        NL*HID*HID, NL*HID, NL*HID, NL*HID, NL*HID,
        HID*64, 64, 64*3, 3
    };
    CvtDesc cd;
    float* fp[24];
    for (int a = 0; a < 24; ++a) {
        fp[a] = alloc((size_t)alen[a]);
        cd.src[a] = d_in[aidx[a]];
        cd.dst[a] = fp[a];
        cd.len[a] = alen[a];
    }
    float* agg = alloc((size_t)NN*HID);
    float* hz  = alloc((size_t)BB*HID);
    float* pos = alloc((size_t)NN*3);
    float* upd = alloc((size_t)NN*3);
    short* hb  = (short*)alloc((size_t)NN*HID/2);
    short* H1  = (short*)alloc((size_t)NN*256/2);
    short* wcatp = (short*)alloc((size_t)NL*32768/2);
    short* w2p = (short*)alloc((size_t)NL*16384/2);
    short* c1p = (short*)alloc((size_t)NL*16384/2);
    short* nw1p = (short*)alloc((size_t)NL*32768/2);
    short* nw2p = (short*)alloc((size_t)NL*16384/2);
    short* hw1p = (short*)alloc((size_t)8192/2);
    int* cnt      = (int*)alloc((size_t)NN);
    int* rowStart = (int*)alloc((size_t)NN + 1);
    int* cursor   = (int*)alloc((size_t)NN);
    int* rS       = (int*)alloc((size_t)NE);
    int* cS       = (int*)alloc((size_t)NE);
    const int* eidx = (const int*)d_in[2];

    k_detect<<<1, 256, 0, stream>>>((const unsigned short*)d_in[0],
                                    (const unsigned int*)d_in[2], flags);
    k_convert<<<dim3((NN*AF + 255)/256, 24), 256, 0, stream>>>(cd, flags);

    PackJobs pj;
    for (int l = 0; l < NL; ++l) {
        int b5 = l*5;
        pj.src[b5+0] = fp[7]  + (size_t)l*257*HID; pj.dst[b5+0] = wcatp + (size_t)l*32768; pj.K[b5+0] = 256; pj.mode[b5+0] = 1;
        pj.src[b5+1] = fp[9]  + (size_t)l*HID*HID; pj.dst[b5+1] = w2p   + (size_t)l*16384; pj.K[b5+1] = 128; pj.mode[b5+1] = 0;
        pj.src[b5+2] = fp[15] + (size_t)l*HID*HID; pj.dst[b5+2] = c1p   + (size_t)l*16384; pj.K[b5+2] = 128; pj.mode[b5+2] = 0;
        pj.src[b5+3] = fp[11] + (size_t)l*256*HID; pj.dst[b5+3] = nw1p  + (size_t)l*32768; pj.K[b5+3] = 256; pj.mode[b5+3] = 0;
        pj.src[b5+4] = fp[13] + (size_t)l*HID*HID; pj.dst[b5+4] = nw2p  + (size_t)l*16384; pj.K[b5+4] = 128; pj.mode[b5+4] = 0;
    }
    pj.src[10] = fp[20]; pj.dst[10] = hw1p; pj.K[10] = 128; pj.mode[10] = 2;
    k_packall<<<dim3(128, 11), 256, 0, stream>>>(pj);

    // counting sort edges by row
    hipMemsetAsync(cnt, 0, (size_t)NN*sizeof(int), stream);
    k_hist<<<(NE + 255)/256, 256, 0, stream>>>(eidx, flags, cnt);
    k_scan<<<1, 1024, 0, stream>>>(cnt, rowStart, cursor);
    k_scatter<<<(NE + 255)/256, 256, 0, stream>>>(eidx, flags, cursor, rS, cS);

    k_hz<<<BB, HID, 0, stream>>>(fp[0], fp[3], fp[4], hz);
    k_init3<<<NN/64, 256, 0, stream>>>(hz, fp[1], fp[5], fp[6], fp[2], pos, hb,
                                       wcatp, fp[8], H1, agg, upd);

    for (int l = 0; l < NL; ++l) {
        k_edge8<<<PBLK, 256, 0, stream>>>(H1, rS, cS, pos,
            fp[7] + (size_t)l*257*HID + 256*HID,       // w1c (d2 row, f32)
            w2p + (size_t)l*16384, fp[10] + (size_t)l*HID,
            c1p + (size_t)l*16384, fp[16] + (size_t)l*HID,
            fp[17] + (size_t)l*HID,
            agg, upd);
        const short* wcatn = (l+1 < NL) ? (wcatp + (size_t)(l+1)*32768) : nullptr;
        const float* b1nx  = (l+1 < NL) ? (fp[8] + (size_t)(l+1)*HID) : fp[8];
        k_node_mfma<<<NN/64, 256, 0, stream>>>(hb, agg,
            nw1p + (size_t)l*32768, fp[12] + (size_t)l*HID,
            nw2p + (size_t)l*16384, fp[14] + (size_t)l*HID,
            fp[18] + (size_t)l*HID, fp[19] + (size_t)l*HID,
            pos, upd, rowStart, wcatn, b1nx, H1,
            hw1p, fp[21], fp[22], fp[23], d_out, flags);
    }
}

// Round 15
// 593.842 us; speedup vs baseline: 1.8491x; 1.0220x over previous
//
#include <hip/hip_runtime.h>
#include <hip/hip_bf16.h>

#define BB 512
#define NA 58
#define LAT 64
#define HID 128
#define AF 10
#define NL 2
#define NN (BB*NA)      // 29696
#define NE (NN*16)      // 475136
#define ET 64           // edges per tile
#define NTILE (NE/ET)   // 7424
#define PBLK 768        // persistent blocks

typedef __attribute__((ext_vector_type(8))) short s8;
typedef __attribute__((ext_vector_type(4))) float f4;

struct CvtDesc {
    const void* src[24];
    float*      dst[24];
    int         len[24];
};

struct PackJobs {
    const float* src[11];
    short*       dst[11];
    int          K[11];
    int          mode[11];   // 0: [K][128] B-frag; 1: edge-w1 concat; 2: [K][64] B-frag
};

__device__ __forceinline__ float siluf(float x) {
    return x * __builtin_amdgcn_rcpf(1.0f + __expf(-x));
}

__device__ __forceinline__ short f2b(float x) {
    __hip_bfloat16 b = __float2bfloat16(x);
    return *(short*)&b;
}

__device__ __forceinline__ float b2f(short s) {
    return __uint_as_float(((unsigned int)(unsigned short)s) << 16);
}

// ---------------------------------------------------------------------------
__global__ void k_detect(const unsigned short* __restrict__ z16,
                         const unsigned int* __restrict__ e32,
                         int* __restrict__ flags) {
    __shared__ int sbf, si64;
    if (threadIdx.x == 0) { sbf = 0; si64 = 0; }
    __syncthreads();
    int c1 = 0, c2 = 0;
    for (int i = threadIdx.x; i < 1024; i += 256) {
        unsigned short v = z16[2*i];
        int e = (v >> 7) & 0xFF;
        if (e >= 100 && e <= 140) c1++;
        if (e32[2*i + 1] == 0u) c2++;
    }
    atomicAdd(&sbf, c1);
    atomicAdd(&si64, c2);
    __syncthreads();
    if (threadIdx.x == 0) {
        flags[0] = (sbf  > 600) ? 1 : 0;
        flags[1] = (si64 > 600) ? 1 : 0;
    }
}

__global__ void k_convert(CvtDesc d, const int* __restrict__ flags) {
    int a = blockIdx.y;
    int i = blockIdx.x * blockDim.x + threadIdx.x;
    int n = d.len[a];
    if (i >= n) return;
    if (flags[0]) {
        d.dst[a][i] = __bfloat162float(((const __hip_bfloat16*)d.src[a])[i]);
    } else {
        d.dst[a][i] = ((const float*)d.src[a])[i];
    }
}

__global__ void k_packall(PackJobs pj) {
    int j = blockIdx.y;
    int idx = blockIdx.x * 256 + threadIdx.x;
    const float* w = pj.src[j];
    short* o = pj.dst[j];
    int mode = pj.mode[j];
    if (mode == 0) {
        int K = pj.K[j];
        if (idx >= 128*K) return;
        int jj = idx & 7;
        int l  = (idx >> 3) & 63;
        int rest = idx >> 9;
        int KC = K >> 5;
        int kc = rest % KC;
        int nt = rest / KC;
        int n = nt*16 + (l & 15);
        int k = kc*32 + (l >> 4)*8 + jj;
        o[idx] = f2b(w[k*128 + n]);
    } else if (mode == 1) {
        if (idx >= 32768) return;
        int jj = idx & 7;
        int l  = (idx >> 3) & 63;
        int rest = idx >> 9;
        int kc = rest & 3;
        int nt = rest >> 2;
        int n = nt*16 + (l & 15);
        int k = kc*32 + (l >> 4)*8 + jj;
        float v = (n < 128) ? w[k*128 + n] : w[(128 + k)*128 + (n - 128)];
        o[idx] = f2b(v);
    } else {
        if (idx >= 8192) return;
        int jj = idx & 7;
        int l  = (idx >> 3) & 63;
        int rest = idx >> 9;
        int kc = rest & 3;
        int nt = rest >> 2;
        int n = nt*16 + (l & 15);
        int k = kc*32 + (l >> 4)*8 + jj;
        o[idx] = f2b(w[k*64 + n]);
    }
}

// ---------------------------------------------------------------------------
__global__ void k_hist(const int* __restrict__ eidx, const int* __restrict__ flags,
                       int* __restrict__ cnt) {
    int e = blockIdx.x * 256 + threadIdx.x;
    if (e >= NE) return;
    int is64 = flags[1];
    int r = eidx[is64 ? 2*(long)e : (long)e];
    atomicAdd(&cnt[r], 1);
}

__global__ __launch_bounds__(1024) void k_scan(const int* __restrict__ cnt,
                                               int* __restrict__ rowStart,
                                               int* __restrict__ cursor) {
    __shared__ int part[1024];
    int t = threadIdx.x;
    int base = t * 29;                    // NN == 1024*29
    int loc[29];
    int s = 0;
    #pragma unroll
    for (int i = 0; i < 29; ++i) { loc[i] = s; s += cnt[base + i]; }
    part[t] = s;
    __syncthreads();
    for (int d = 1; d < 1024; d <<= 1) {
        int v = (t >= d) ? part[t - d] : 0;
        __syncthreads();
        part[t] += v;
        __syncthreads();
    }
    int pre = (t == 0) ? 0 : part[t - 1];
    #pragma unroll
    for (int i = 0; i < 29; ++i) {
        int v = pre + loc[i];
        rowStart[base + i] = v;
        cursor[base + i] = v;
    }
    if (t == 1023) rowStart[NN] = pre + s;
}

__global__ void k_scatter(const int* __restrict__ eidx, const int* __restrict__ flags,
                          int* __restrict__ cursor,
                          int* __restrict__ rS, int* __restrict__ cS) {
    int e = blockIdx.x * 256 + threadIdx.x;
    if (e >= NE) return;
    int is64 = flags[1];
    long ge = e, gc = (long)e + NE;
    int r = eidx[is64 ? 2*ge : ge];
    int c = eidx[is64 ? 2*gc : gc];
    int p = atomicAdd(&cursor[r], 1);
    rS[p] = r; cS[p] = c;
}

// ---------------------------------------------------------------------------
// init3: fused hz GEMV + h init (bf16) + pos init + zero agg/upd + H1(l0) GEMM.
__global__ __launch_bounds__(256) void k_init3(
    const float* __restrict__ z, const float* __restrict__ lw,
    const float* __restrict__ lbz,
    const float* __restrict__ at,
    const float* __restrict__ aw, const float* __restrict__ ab,
    const float* __restrict__ ic,
    float* __restrict__ pos, short* __restrict__ hb,
    const short* __restrict__ wcat0, const float* __restrict__ b10,
    short* __restrict__ H1, float* __restrict__ agg, float* __restrict__ upd)
{
    __shared__ short x[64][136];
    __shared__ float awS[AF][HID];
    __shared__ float atS[64][AF+2];
    __shared__ float zbS[3][LAT];
    __shared__ float hzS[3][HID];
    const int tid = threadIdx.x;
    const int n0 = blockIdx.x * 64;
    const int b0 = n0 / NA;
    const int nb = (n0 + 63) / NA - b0 + 1;   // 1..3

    for (int i = tid; i < AF*HID; i += 256) awS[i/HID][i%HID] = aw[i];
    for (int i = tid; i < 64*AF; i += 256)
        atS[i/AF][i%AF] = at[(long)(n0 + i/AF)*AF + i%AF];
    for (int i = tid; i < nb*LAT; i += 256) {
        int bi = i / LAT, k = i - bi*LAT;
        int bidx = b0 + bi;
        zbS[bi][k] = (bidx < BB) ? z[bidx*LAT + k] : 0.f;
    }
    __syncthreads();

    for (int i = tid; i < nb*HID; i += 256) {
        int bi = i / HID, c = i - bi*HID;
        float acc = lbz[c];
        #pragma unroll
        for (int k = 0; k < LAT; ++k) acc += zbS[bi][k] * lw[k*HID + c];
        hzS[bi][c] = acc;
    }
    __syncthreads();

    #pragma unroll
    for (int it = 0; it < 32; ++it) {
        int idx = it*256 + tid;
        int r = idx >> 7, c = idx & 127;
        int n = n0 + r;
        float v = hzS[n/NA - b0][c] + ab[c];
        #pragma unroll
        for (int f = 0; f < AF; ++f) v += atS[r][f]*awS[f][c];
        short s = f2b(v);
        x[r][c] = s;
        hb[(long)n*HID + c] = s;
    }
    if (tid < 192) {
        int i = tid/3, d = tid - i*3;
        int n = n0 + i;
        pos[n*3 + d] = ic[(n % NA)*3 + d];
        upd[n*3 + d] = 0.f;
    }
    {
        f4* a4 = (f4*)(agg + (long)n0*HID);
        for (int j = tid; j < 64*HID/4; j += 256) a4[j] = (f4)0.f;
    }
    __syncthreads();

    const int l = tid & 63, w = tid >> 6;
    const int l16 = l & 15, quad = l >> 4;
    f4 acc[4][4];
    #pragma unroll
    for (int mt = 0; mt < 4; ++mt)
        #pragma unroll
        for (int nt4 = 0; nt4 < 4; ++nt4) acc[mt][nt4] = (f4)0.f;
    #pragma unroll
    for (int kc = 0; kc < 4; ++kc) {
        s8 a[4];
        #pragma unroll
        for (int mt = 0; mt < 4; ++mt)
            a[mt] = *(const s8*)&x[mt*16 + l16][kc*32 + quad*8];
        #pragma unroll
        for (int nt4 = 0; nt4 < 4; ++nt4) {
            int nt = w*4 + nt4;
            s8 b = *(const s8*)(wcat0 + (((size_t)nt*4 + kc)*64 + l)*8);
            #pragma unroll
            for (int mt = 0; mt < 4; ++mt)
                acc[mt][nt4] = __builtin_amdgcn_mfma_f32_16x16x32_bf16(a[mt], b, acc[mt][nt4], 0, 0, 0);
        }
    }
    #pragma unroll
    for (int nt4 = 0; nt4 < 4; ++nt4) {
        int col = (w*4 + nt4)*16 + l16;
        float bias = (col < 128) ? b10[col] : 0.f;
        #pragma unroll
        for (int mt = 0; mt < 4; ++mt)
            #pragma unroll
            for (int i = 0; i < 4; ++i) {
                int row = mt*16 + quad*4 + i;
                H1[(long)(n0 + row)*256 + col] = f2b(acc[mt][nt4][i] + bias);
            }
    }
}

// ---------------------------------------------------------------------------
// Edge kernel v8r: double-buffered t1, 2 barriers/tile; agg atomics issued
// BEFORE stage3 so their vmcnt drains under the MFMA shadow.
__global__ __launch_bounds__(256, 3) void k_edge8(
    const short* __restrict__ H1,
    const int* __restrict__ rS, const int* __restrict__ cS,
    const float* __restrict__ pos,
    const float* __restrict__ w1c,
    const short* __restrict__ w2p, const float* __restrict__ b2,
    const short* __restrict__ c1p, const float* __restrict__ cb1,
    const float* __restrict__ cw2,
    float* __restrict__ agg, float* __restrict__ upd)
{
    __shared__ short t1[2][ET][136];
    __shared__ short mm[ET][136];
    __shared__ int   rIs[2][ET], cIs[2][ET];
    __shared__ float sred[ET];

    const int tid = threadIdx.x;
    const int l = tid & 63, w = tid >> 6;
    const int l16 = l & 15, quad = l >> 4;
    const int c0 = (2*w)*16 + l16, c1c = (2*w+1)*16 + l16;
    const int half = tid >> 7, ch = tid & 127;
    const int q = tid & 15;
    const int esub = tid >> 4;

    float wv[8];
    #pragma unroll
    for (int j = 0; j < 8; ++j) wv[j] = w1c[q*8 + j];

    s8 w2f[8], c1f[8];
    #pragma unroll
    for (int kc = 0; kc < 4; ++kc) {
        w2f[kc]     = *(const s8*)(w2p + (((size_t)(2*w)*4 + kc)*64 + l)*8);
        w2f[4 + kc] = *(const s8*)(w2p + (((size_t)(2*w+1)*4 + kc)*64 + l)*8);
        c1f[kc]     = *(const s8*)(c1p + (((size_t)(2*w)*4 + kc)*64 + l)*8);
        c1f[4 + kc] = *(const s8*)(c1p + (((size_t)(2*w+1)*4 + kc)*64 + l)*8);
    }
    const float bia2_0 = b2[c0],  bia2_1 = b2[c1c];
    const float biac_0 = cb1[c0], biac_1 = cb1[c1c];
    const float cw0    = cw2[c0], cw1v   = cw2[c1c];

    int   pri[4], pci[4];
    float pd2[4];
    auto PREIDX = [&](int T) {
        long eb = (long)T * ET;
        #pragma unroll
        for (int it = 0; it < 4; ++it) {
            int e = esub + 16*it;
            int r = rS[eb + e], c = cS[eb + e];
            pri[it] = r; pci[it] = c;
            float rx = pos[r*3+0] - pos[c*3+0];
            float ry = pos[r*3+1] - pos[c*3+1];
            float rz = pos[r*3+2] - pos[c*3+2];
            pd2[it] = fminf(fmaxf(rx*rx + ry*ry + rz*rz, 1e-6f), 1e6f);
        }
    };

    // prologue: build tile T into t1[0]
    int T = blockIdx.x;
    PREIDX(T);
    #pragma unroll
    for (int it = 0; it < 4; ++it) {
        s8 va = *(const s8*)(H1 + (long)pri[it]*256 + q*8);
        s8 vb = *(const s8*)(H1 + (long)pci[it]*256 + 128 + q*8);
        float d2 = pd2[it];
        s8 o;
        #pragma unroll
        for (int j = 0; j < 8; ++j)
            o[j] = f2b(siluf(b2f(va[j]) + b2f(vb[j]) + d2*wv[j]));
        *(s8*)&t1[0][esub + 16*it][q*8] = o;
    }
    if (q == 0) {
        #pragma unroll
        for (int it = 0; it < 4; ++it) {
            rIs[0][esub + 16*it] = pri[it];
            cIs[0][esub + 16*it] = pci[it];
        }
    }
    if (tid < ET) sred[tid] = 0.f;
    int Tn = T + PBLK;
    if (Tn < NTILE) PREIDX(Tn);
    __syncthreads();

    int b = 0;
    while (true) {
        const bool hasNext = (Tn < NTILE);

        // half1: stage2(T) from t1[b] ⊗ build t1[b^1](Tn)
        {
            f4 acc[4][2];
            #pragma unroll
            for (int mt = 0; mt < 4; ++mt) { acc[mt][0] = (f4)0.f; acc[mt][1] = (f4)0.f; }
            #pragma unroll
            for (int it = 0; it < 4; ++it) {
                s8 va, vb;
                if (hasNext) {
                    va = *(const s8*)(H1 + (long)pri[it]*256 + q*8);
                    vb = *(const s8*)(H1 + (long)pci[it]*256 + 128 + q*8);
                }
                #pragma unroll
                for (int mt = 0; mt < 4; ++mt) {
                    s8 a = *(const s8*)&t1[b][mt*16 + l16][it*32 + quad*8];
                    acc[mt][0] = __builtin_amdgcn_mfma_f32_16x16x32_bf16(a, w2f[it],     acc[mt][0], 0, 0, 0);
                    acc[mt][1] = __builtin_amdgcn_mfma_f32_16x16x32_bf16(a, w2f[4 + it], acc[mt][1], 0, 0, 0);
                }
                if (hasNext) {
                    float d2 = pd2[it];
                    s8 o;
                    #pragma unroll
                    for (int j = 0; j < 8; ++j)
                        o[j] = f2b(siluf(b2f(va[j]) + b2f(vb[j]) + d2*wv[j]));
                    *(s8*)&t1[b^1][esub + 16*it][q*8] = o;
                }
            }
            if (hasNext && q == 0) {
                #pragma unroll
                for (int it = 0; it < 4; ++it) {
                    rIs[b^1][esub + 16*it] = pri[it];
                    cIs[b^1][esub + 16*it] = pci[it];
                }
            }
            #pragma unroll
            for (int mt = 0; mt < 4; ++mt) {
                #pragma unroll
                for (int i = 0; i < 4; ++i) {
                    int row = mt*16 + quad*4 + i;
                    mm[row][c0]  = f2b(siluf(acc[mt][0][i] + bia2_0));
                    mm[row][c1c] = f2b(siluf(acc[mt][1][i] + bia2_1));
                }
            }
        }
        __syncthreads();                 // (1) mm + t1[b^1] + meta ready

        // half2a: agg(T) FIRST — atomics drain under stage3's MFMA shadow
        {
            int e0 = half * 32;
            int cur = rIs[b][e0];
            float a = 0.f;
            #pragma unroll
            for (int e = e0; e < e0 + 32; ++e) {
                int r = rIs[b][e];
                if (r != cur) {
                    atomicAdd(&agg[(long)cur*HID + ch], a);
                    a = 0.f; cur = r;
                }
                a += b2f(mm[e][ch]);
            }
            atomicAdd(&agg[(long)cur*HID + ch], a);
        }
        // half2b: stage3(T)
        {
            f4 acc[4][2];
            #pragma unroll
            for (int mt = 0; mt < 4; ++mt) { acc[mt][0] = (f4)0.f; acc[mt][1] = (f4)0.f; }
            #pragma unroll
            for (int kc = 0; kc < 4; ++kc) {
                #pragma unroll
                for (int mt = 0; mt < 4; ++mt) {
                    s8 a = *(const s8*)&mm[mt*16 + l16][kc*32 + quad*8];
                    acc[mt][0] = __builtin_amdgcn_mfma_f32_16x16x32_bf16(a, c1f[kc],     acc[mt][0], 0, 0, 0);
                    acc[mt][1] = __builtin_amdgcn_mfma_f32_16x16x32_bf16(a, c1f[4 + kc], acc[mt][1], 0, 0, 0);
                }
            }
            #pragma unroll
            for (int mt = 0; mt < 4; ++mt) {
                #pragma unroll
                for (int i = 0; i < 4; ++i) {
                    float p = siluf(acc[mt][0][i] + biac_0) * cw0
                            + siluf(acc[mt][1][i] + biac_1) * cw1v;
                    p += __shfl_xor(p, 1);
                    p += __shfl_xor(p, 2);
                    p += __shfl_xor(p, 4);
                    p += __shfl_xor(p, 8);
                    if (l16 == 0) {
                        int row = mt*16 + quad*4 + i;
                        atomicAdd(&sred[row], p);
                    }
                }
            }
        }
        int Tnn = Tn + PBLK;
        if (hasNext && Tnn < NTILE) PREIDX(Tnn);
        __syncthreads();                 // (2) sred complete, mm consumed

        if (tid < ET) {
            float cwv = fminf(fmaxf(sred[tid], -1.f), 1.f);
            sred[tid] = 0.f;
            int r = rIs[b][tid], c = cIs[b][tid];
            float rx = pos[r*3+0] - pos[c*3+0];
            float ry = pos[r*3+1] - pos[c*3+1];
            float rz = pos[r*3+2] - pos[c*3+2];
            atomicAdd(&upd[r*3+0], cwv*rx);
            atomicAdd(&upd[r*3+1], cwv*ry);
            atomicAdd(&upd[r*3+2], cwv*rz);
        }
        if (!hasNext) break;
        T = Tn; Tn = Tnn; b ^= 1;
    }
}

// ---------------------------------------------------------------------------
// Node kernel + fused H1(next layer) or fused head (last layer).
__global__ __launch_bounds__(256) void k_node_mfma(
    short* __restrict__ hb, float* __restrict__ agg,
    const short* __restrict__ w1p, const float* __restrict__ b1n,
    const short* __restrict__ w2p, const float* __restrict__ b2n,
    const float* __restrict__ lg, const float* __restrict__ lb,
    float* __restrict__ pos, float* __restrict__ upd,
    const int* __restrict__ rowStart,
    const short* __restrict__ wcatn, const float* __restrict__ b1next,
    short* __restrict__ H1,
    const short* __restrict__ hw1p, const float* __restrict__ hb1,
    const float* __restrict__ hw2, const float* __restrict__ hb2,
    void* __restrict__ out, const int* __restrict__ flags)
{
    __shared__ short x[64][264];
    __shared__ short t1[64][144];
    __shared__ float mus[64], rstds[64];
    __shared__ float posS[64][3];
    float (*hn)[132] = (float (*)[132])&x[0][0];
    float (*hid)[68] = (float (*)[68])&x[0][0];

    const int tid = threadIdx.x;
    const int n0 = blockIdx.x * 64;

    #pragma unroll
    for (int it = 0; it < 4; ++it) {
        int idx = it*256 + tid;
        int e = idx >> 4, qq = idx & 15;
        *(int4*)&x[e][qq*8] = *(const int4*)(hb + (long)(n0+e)*HID + qq*8);
    }
    #pragma unroll
    for (int it = 0; it < 8; ++it) {
        int idx = it*256 + tid;
        int e = idx >> 5, qq = idx & 31;
        float4 v = *(const float4*)(agg + (long)(n0+e)*HID + qq*4);
        short4 sv;
        sv.x = f2b(v.x); sv.y = f2b(v.y); sv.z = f2b(v.z); sv.w = f2b(v.w);
        *(short4*)&x[e][128 + qq*4] = sv;
    }
    __syncthreads();

    {
        f4* a4 = (f4*)(agg + (long)n0*HID);
        for (int j = tid; j < 64*HID/4; j += 256) a4[j] = (f4)0.f;
    }

    const int l = tid & 63, w = tid >> 6;
    const int l16 = l & 15, quad = l >> 4;
    const int nt0 = 2*w, nt1 = 2*w + 1;
    const int c0 = nt0*16 + l16, c1c = nt1*16 + l16;

    {
        f4 acc[4][2];
        #pragma unroll
        for (int mt = 0; mt < 4; ++mt) { acc[mt][0] = (f4)0.f; acc[mt][1] = (f4)0.f; }
        #pragma unroll
        for (int kc = 0; kc < 8; ++kc) {
            s8 b0  = *(const s8*)(w1p + (((size_t)nt0*8 + kc)*64 + l)*8);
            s8 b1f = *(const s8*)(w1p + (((size_t)nt1*8 + kc)*64 + l)*8);
            #pragma unroll
            for (int mt = 0; mt < 4; ++mt) {
                s8 a = *(const s8*)&x[mt*16 + l16][kc*32 + quad*8];
                acc[mt][0] = __builtin_amdgcn_mfma_f32_16x16x32_bf16(a, b0,  acc[mt][0], 0, 0, 0);
                acc[mt][1] = __builtin_amdgcn_mfma_f32_16x16x32_bf16(a, b1f, acc[mt][1], 0, 0, 0);
            }
        }
        float bia0 = b1n[c0], bia1 = b1n[c1c];
        #pragma unroll
        for (int mt = 0; mt < 4; ++mt) {
            #pragma unroll
            for (int i = 0; i < 4; ++i) {
                int row = mt*16 + quad*4 + i;
                t1[row][c0]  = f2b(siluf(acc[mt][0][i] + bia0));
                t1[row][c1c] = f2b(siluf(acc[mt][1][i] + bia1));
            }
        }
    }
    __syncthreads();

    {
        f4 acc[4][2];
        #pragma unroll
        for (int mt = 0; mt < 4; ++mt) { acc[mt][0] = (f4)0.f; acc[mt][1] = (f4)0.f; }
        #pragma unroll
        for (int kc = 0; kc < 4; ++kc) {
            s8 b0  = *(const s8*)(w2p + (((size_t)nt0*4 + kc)*64 + l)*8);
            s8 b1f = *(const s8*)(w2p + (((size_t)nt1*4 + kc)*64 + l)*8);
            #pragma unroll
            for (int mt = 0; mt < 4; ++mt) {
                s8 a = *(const s8*)&t1[mt*16 + l16][kc*32 + quad*8];
                acc[mt][0] = __builtin_amdgcn_mfma_f32_16x16x32_bf16(a, b0,  acc[mt][0], 0, 0, 0);
                acc[mt][1] = __builtin_amdgcn_mfma_f32_16x16x32_bf16(a, b1f, acc[mt][1], 0, 0, 0);
            }
        }
        float bia0 = b2n[c0], bia1 = b2n[c1c];
        __syncthreads();
        #pragma unroll
        for (int mt = 0; mt < 4; ++mt) {
            #pragma unroll
            for (int i = 0; i < 4; ++i) {
                int row = mt*16 + quad*4 + i;
                hn[row][c0]  = acc[mt][0][i] + bia0;
                hn[row][c1c] = acc[mt][1][i] + bia1;
            }
        }
    }
    __syncthreads();

    {
        int r = tid >> 2, part = tid & 3;
        float s = 0.f, qv = 0.f;
        #pragma unroll
        for (int j = 0; j < 32; ++j) {
            float v = hn[r][part + 4*j];
            s += v; qv += v*v;
        }
        s += __shfl_xor(s, 1); qv += __shfl_xor(qv, 1);
        s += __shfl_xor(s, 2); qv += __shfl_xor(qv, 2);
        if (part == 0) {
            float mu = s * (1.0f/HID);
            float var = qv * (1.0f/HID) - mu*mu;
            mus[r] = mu;
            rstds[r] = rsqrtf(var + 1e-5f);
        }
    }
    __syncthreads();

    #pragma unroll
    for (int it = 0; it < 32; ++it) {
        int idx = it*256 + tid;
        int r = idx >> 7, c = idx & 127;
        float v = (hn[r][c] - mus[r]) * rstds[r] * lg[c] + lb[c];
        short s = f2b(v);
        hb[(long)(n0 + r)*HID + c] = s;
        t1[r][c] = s;
    }
    if (tid < 192) {
        int i = tid / 3, d = tid - i*3;
        int n = n0 + i;
        float dg = (float)(rowStart[n+1] - rowStart[n]);
        float np = pos[n*3+d] + upd[n*3+d] / (dg + 1e-6f);
        pos[n*3+d] = np;
        posS[i][d] = np;
        upd[n*3+d] = 0.f;
    }
    __syncthreads();

    if (wcatn) {
        f4 acc[4][4];
        #pragma unroll
        for (int mt = 0; mt < 4; ++mt)
            #pragma unroll
            for (int nt4 = 0; nt4 < 4; ++nt4) acc[mt][nt4] = (f4)0.f;
        #pragma unroll
        for (int kc = 0; kc < 4; ++kc) {
            s8 a[4];
            #pragma unroll
            for (int mt = 0; mt < 4; ++mt)
                a[mt] = *(const s8*)&t1[mt*16 + l16][kc*32 + quad*8];
            #pragma unroll
            for (int nt4 = 0; nt4 < 4; ++nt4) {
                int nt = w*4 + nt4;
                s8 b = *(const s8*)(wcatn + (((size_t)nt*4 + kc)*64 + l)*8);
                #pragma unroll
                for (int mt = 0; mt < 4; ++mt)
                    acc[mt][nt4] = __builtin_amdgcn_mfma_f32_16x16x32_bf16(a[mt], b, acc[mt][nt4], 0, 0, 0);
            }
        }
        #pragma unroll
        for (int nt4 = 0; nt4 < 4; ++nt4) {
            int col = (w*4 + nt4)*16 + l16;
            float bias = (col < 128) ? b1next[col] : 0.f;
            #pragma unroll
            for (int mt = 0; mt < 4; ++mt)
                #pragma unroll
                for (int i = 0; i < 4; ++i) {
                    int row = mt*16 + quad*4 + i;
                    H1[(long)(n0 + row)*256 + col] = f2b(acc[mt][nt4][i] + bias);
                }
        }
    } else {
        f4 acc[4];
        #pragma unroll
        for (int mt = 0; mt < 4; ++mt) acc[mt] = (f4)0.f;
        #pragma unroll
        for (int kc = 0; kc < 4; ++kc) {
            s8 b = *(const s8*)(hw1p + (((size_t)w*4 + kc)*64 + l)*8);
            #pragma unroll
            for (int mt = 0; mt < 4; ++mt) {
                s8 a = *(const s8*)&t1[mt*16 + l16][kc*32 + quad*8];
                acc[mt] = __builtin_amdgcn_mfma_f32_16x16x32_bf16(a, b, acc[mt], 0, 0, 0);
            }
        }
        int col = w*16 + l16;
        float bias = hb1[col];
        #pragma unroll
        for (int mt = 0; mt < 4; ++mt)
            #pragma unroll
            for (int i = 0; i < 4; ++i) {
                int row = mt*16 + quad*4 + i;
                hid[row][col] = siluf(acc[mt][i] + bias);
            }
        __syncthreads();
        if (tid < 192) {
            int r = tid / 3, cc = tid - r*3;
            float a2 = hb2[cc];
            #pragma unroll
            for (int k = 0; k < 64; ++k) a2 += hid[r][k] * hw2[k*3 + cc];
            int n = n0 + r;
            float v = posS[r][cc] + a2;
            if (flags[0]) ((__hip_bfloat16*)out)[n*3+cc] = __float2bfloat16(v);
            else          ((float*)out)[n*3+cc] = v;
        }
    }
}

// ---------------------------------------------------------------------------
extern "C" void kernel_launch(void* const* d_in, const int* in_sizes, int n_in,
                              void* d_out, int out_size, void* d_ws, size_t ws_size,
                              hipStream_t stream)
{
    (void)in_sizes; (void)n_in; (void)out_size; (void)ws_size;

    int* flags = (int*)d_ws;
    float* base = (float*)d_ws;
    size_t off = 64;
    auto alloc = [&](size_t n) { float* p = base + off; off += (n + 63) & ~63ull; return p; };

    static const int aidx[24] = {0,1,3,4,5,6,7,8,9,10,11,12,13,14,15,16,17,18,19,20,21,22,23,24};
    static const int alen[24] = {
        BB*LAT, NN*AF, NA*3, LAT*HID, HID, AF*HID, HID,
        NL*257*HID, NL*HID, NL*HID*HID, NL*HID,
        NL*256*HID, NL*HID, NL*HID*HID, NL*HID,
        NL*HID*HID, NL*HID, NL*HID, NL*HID, NL*HID,
        HID*64, 64, 64*3, 3
    };
    CvtDesc cd;
    float* fp[24];
    for (int a = 0; a < 24; ++a) {
        fp[a] = alloc((size_t)alen[a]);
        cd.src[a] = d_in[aidx[a]];
        cd.dst[a] = fp[a];
        cd.len[a] = alen[a];
    }
    float* agg = alloc((size_t)NN*HID);
    float* pos = alloc((size_t)NN*3);
    float* upd = alloc((size_t)NN*3);
    short* hb  = (short*)alloc((size_t)NN*HID/2);
    short* H1  = (short*)alloc((size_t)NN*256/2);
    short* wcatp = (short*)alloc((size_t)NL*32768/2);
    short* w2p = (short*)alloc((size_t)NL*16384/2);
    short* c1p = (short*)alloc((size_t)NL*16384/2);
    short* nw1p = (short*)alloc((size_t)NL*32768/2);
    short* nw2p = (short*)alloc((size_t)NL*16384/2);
    short* hw1p = (short*)alloc((size_t)8192/2);
    int* cnt      = (int*)alloc((size_t)NN);
    int* rowStart = (int*)alloc((size_t)NN + 1);
    int* cursor   = (int*)alloc((size_t)NN);
    int* rS       = (int*)alloc((size_t)NE);
    int* cS       = (int*)alloc((size_t)NE);
    const int* eidx = (const int*)d_in[2];

    k_detect<<<1, 256, 0, stream>>>((const unsigned short*)d_in[0],
                                    (const unsigned int*)d_in[2], flags);
    k_convert<<<dim3((NN*AF + 255)/256, 24), 256, 0, stream>>>(cd, flags);

    PackJobs pj;
    for (int l = 0; l < NL; ++l) {
        int b5 = l*5;
        pj.src[b5+0] = fp[7]  + (size_t)l*257*HID; pj.dst[b5+0] = wcatp + (size_t)l*32768; pj.K[b5+0] = 256; pj.mode[b5+0] = 1;
        pj.src[b5+1] = fp[9]  + (size_t)l*HID*HID; pj.dst[b5+1] = w2p   + (size_t)l*16384; pj.K[b5+1] = 128; pj.mode[b5+1] = 0;
        pj.src[b5+2] = fp[15] + (size_t)l*HID*HID; pj.dst[b5+2] = c1p   + (size_t)l*16384; pj.K[b5+2] = 128; pj.mode[b5+2] = 0;
        pj.src[b5+3] = fp[11] + (size_t)l*256*HID; pj.dst[b5+3] = nw1p  + (size_t)l*32768; pj.K[b5+3] = 256; pj.mode[b5+3] = 0;
        pj.src[b5+4] = fp[13] + (size_t)l*HID*HID; pj.dst[b5+4] = nw2p  + (size_t)l*16384; pj.K[b5+4] = 128; pj.mode[b5+4] = 0;
    }
    pj.src[10] = fp[20]; pj.dst[10] = hw1p; pj.K[10] = 128; pj.mode[10] = 2;
    k_packall<<<dim3(128, 11), 256, 0, stream>>>(pj);

    // counting sort edges by row
    hipMemsetAsync(cnt, 0, (size_t)NN*sizeof(int), stream);
    k_hist<<<(NE + 255)/256, 256, 0, stream>>>(eidx, flags, cnt);
    k_scan<<<1, 1024, 0, stream>>>(cnt, rowStart, cursor);
    k_scatter<<<(NE + 255)/256, 256, 0, stream>>>(eidx, flags, cursor, rS, cS);

    k_init3<<<NN/64, 256, 0, stream>>>(fp[0], fp[3], fp[4],
                                       fp[1], fp[5], fp[6], fp[2], pos, hb,
                                       wcatp, fp[8], H1, agg, upd);

    for (int l = 0; l < NL; ++l) {
        k_edge8<<<PBLK, 256, 0, stream>>>(H1, rS, cS, pos,
            fp[7] + (size_t)l*257*HID + 256*HID,       // w1c (d2 row, f32)
            w2p + (size_t)l*16384, fp[10] + (size_t)l*HID,
            c1p + (size_t)l*16384, fp[16] + (size_t)l*HID,
            fp[17] + (size_t)l*HID,
            agg, upd);
        const short* wcatn = (l+1 < NL) ? (wcatp + (size_t)(l+1)*32768) : nullptr;
        const float* b1nx  = (l+1 < NL) ? (fp[8] + (size_t)(l+1)*HID) : fp[8];
        k_node_mfma<<<NN/64, 256, 0, stream>>>(hb, agg,
            nw1p + (size_t)l*32768, fp[12] + (size_t)l*HID,
            nw2p + (size_t)l*16384, fp[14] + (size_t)l*HID,
            fp[18] + (size_t)l*HID, fp[19] + (size_t)l*HID,
            pos, upd, rowStart, wcatn, b1nx, H1,
            hw1p, fp[21], fp[22], fp[23], d_out, flags);
    }
}